// Round 1
// 303.786 us; speedup vs baseline: 1.0056x; 1.0056x over previous
//
#include <hip/hip_runtime.h>
#include <hip/hip_bf16.h>
#include <stdint.h>

typedef __attribute__((ext_vector_type(8))) __bf16 bf8v;   // MFMA A/B frag: 8 bf16 = 4 VGPR
typedef __attribute__((ext_vector_type(4))) float f4v;     // MFMA C/D frag

#define L2E 1.44269504088896f

// fp32 -> bf16 round-to-nearest-even (bit pattern as ushort)
__device__ __forceinline__ unsigned short f2bf(float f) {
  union { float f; unsigned u; } v; v.f = f;
  unsigned r = v.u + 0x7fffu + ((v.u >> 16) & 1u);
  return (unsigned short)(r >> 16);
}

// pack two fp32 -> dword of two RNE bf16 (low = f0), HW v_cvt_pk_bf16_f32 path
__device__ __forceinline__ unsigned pk2bf(float f0, float f1) {
  union { __hip_bfloat162 h; unsigned u; } c;
  c.h = __float22bfloat162_rn(make_float2(f0, f1));
  return c.u;
}

// 2^x via v_exp_f32 (native semantic of the HW transcendental)
__device__ __forceinline__ float exp2_hw(float x) {
  return __builtin_amdgcn_exp2f(x);
}

// async global->LDS, 16B per lane; LDS dest = wave-uniform base + lane*16
__device__ __forceinline__ void gl_lds16(const void* g, void* l) {
  __builtin_amdgcn_global_load_lds(
      (__attribute__((address_space(1))) void*)(g),
      (__attribute__((address_space(3))) void*)(l), 16, 0, 0);
}

// ---------------- elementwise cast ----------------
__global__ void cast_bf16_kernel(const float* __restrict__ in,
                                 unsigned short* __restrict__ out) {
  int i = blockIdx.x * 256 + threadIdx.x;
  float4 v = ((const float4*)in)[i];
  ushort4 o;
  o.x = f2bf(v.x); o.y = f2bf(v.y); o.z = f2bf(v.z); o.w = f2bf(v.w);
  ((ushort4*)out)[i] = o;
}

// ---------------- fused weight transpose+cast: w_in (1024x3072) and w_out (1024x1024) ----------------
// blocks x<96 -> w_in, x>=96 -> w_out. Both R=1024 rows.
__global__ void transpose_w_kernel(const float* __restrict__ w_in,
                                   const float* __restrict__ w_out,
                                   unsigned short* __restrict__ wiT,
                                   unsigned short* __restrict__ woT) {
  __shared__ float tile[32][33];
  int bx = blockIdx.x;
  const float* in; unsigned short* out; int C, c0;
  if (bx < 96) { in = w_in;  out = wiT; C = 3072; c0 = bx * 32; }
  else         { in = w_out; out = woT; C = 1024; c0 = (bx - 96) * 32; }
  int r0 = blockIdx.y * 32;
  int tx = threadIdx.x, ty = threadIdx.y;
#pragma unroll
  for (int j = 0; j < 4; ++j)
    tile[ty + 8 * j][tx] = in[(size_t)(r0 + ty + 8 * j) * C + c0 + tx];
  __syncthreads();
#pragma unroll
  for (int j = 0; j < 4; ++j)
    out[(size_t)(c0 + ty + 8 * j) * 1024 + r0 + tx] = f2bf(tile[tx][ty + 8 * j]);
}

// ---------------- V transpose: qkv v-part -> vtg[b][h][d][n] (bf16) ----------------
__global__ void transpose_v_kernel(const unsigned short* __restrict__ qkv,
                                   unsigned short* __restrict__ vtg) {
  __shared__ unsigned short tile[32][33];
  int bh = blockIdx.z;            // b*16 + h
  int d0 = blockIdx.y * 32;       // 0 or 32
  int n0 = blockIdx.x * 32;
  int b = bh >> 4, h = bh & 15;
  int tx = threadIdx.x, ty = threadIdx.y;
  const unsigned short* src = qkv + (size_t)b * 2048 * 3072 + 2048 + h * 64 + d0;
#pragma unroll
  for (int j = 0; j < 4; ++j)
    tile[ty + 8 * j][tx] = src[(size_t)(n0 + ty + 8 * j) * 3072 + tx];
  __syncthreads();
  unsigned short* dst = vtg + ((size_t)bh * 64) * 2048;
#pragma unroll
  for (int j = 0; j < 4; ++j)
    dst[(size_t)(d0 + ty + 8 * j) * 2048 + n0 + tx] = tile[tx][ty + 8 * j];
}

// ---------------- GEMM1: C = A(MxK)*BT(NxK)^T + bias, bf16 out; cols < scale_ncols scaled ----------------
// m97 structure: 128x128 tile, BK=32, global_load_lds 16B, 4 waves of 64x64.
__global__ __launch_bounds__(256, 2) void gemm_bt(
    const unsigned short* __restrict__ A,
    const unsigned short* __restrict__ BT,
    const float* __restrict__ bias,
    unsigned short* __restrict__ C,
    int M, int N, int K, int scale_ncols, float scale) {
  __shared__ __align__(16) unsigned short As[128 * 32];  // [m][k]
  __shared__ __align__(16) unsigned short Bs[128 * 32];  // [n][k]
  const int tid = threadIdx.x;
  const int wave = tid >> 6, lane = tid & 63;
  const int lo = lane & 15, hi = lane >> 4;
  const int m0 = blockIdx.y * 128, n0 = blockIdx.x * 128;
  const int wm = (wave >> 1) * 64, wn = (wave & 1) * 64;

  f4v acc[4][4] = {};

  const int srow = lane >> 2;        // 0..15 rows per wave-load
  const int scol = (lane & 3) * 8;   // shorts (16B chunks)

  for (int k0 = 0; k0 < K; k0 += 32) {
#pragma unroll
    for (int p = 0; p < 2; ++p) {
      int r = p * 64 + wave * 16 + srow;
      gl_lds16(A + (size_t)(m0 + r) * K + k0 + scol,
               &As[(p * 64 + wave * 16) * 32]);
      gl_lds16(BT + (size_t)(n0 + r) * K + k0 + scol,
               &Bs[(p * 64 + wave * 16) * 32]);
    }
    __syncthreads();
    bf8v a[4], b[4];
#pragma unroll
    for (int i = 0; i < 4; ++i)
      a[i] = *(const bf8v*)&As[(wm + i * 16 + lo) * 32 + hi * 8];
#pragma unroll
    for (int j = 0; j < 4; ++j)
      b[j] = *(const bf8v*)&Bs[(wn + j * 16 + lo) * 32 + hi * 8];
#pragma unroll
    for (int i = 0; i < 4; ++i)
#pragma unroll
      for (int j = 0; j < 4; ++j)
        acc[i][j] = __builtin_amdgcn_mfma_f32_16x16x32_bf16(a[i], b[j], acc[i][j], 0, 0, 0);
    __syncthreads();
  }

#pragma unroll
  for (int i = 0; i < 4; ++i) {
#pragma unroll
    for (int r = 0; r < 4; ++r) {
      int row = m0 + wm + i * 16 + hi * 4 + r;   // C/D: row = quad*4+reg
#pragma unroll
      for (int j = 0; j < 4; ++j) {
        int col = n0 + wn + j * 16 + lo;         // C/D: col = lane&15
        float v = acc[i][j][r] + bias[col];
        if (col < scale_ncols) v *= scale;       // fold log2(e) into Q columns
        C[(size_t)row * N + col] = f2bf(v);
      }
    }
  }
}

// ---------------- GEMM2: 64x128 tile, fp32 out (better occupancy at M=8192,N=1024) ----------------
__global__ __launch_bounds__(256, 4) void gemm_bt_sm(
    const unsigned short* __restrict__ A,
    const unsigned short* __restrict__ BT,
    const float* __restrict__ bias,
    float* __restrict__ C,
    int M, int N, int K) {
  __shared__ __align__(16) unsigned short As[64 * 32];   // [m][k]
  __shared__ __align__(16) unsigned short Bs[128 * 32];  // [n][k]
  const int tid = threadIdx.x;
  const int wave = tid >> 6, lane = tid & 63;
  const int lo = lane & 15, hi = lane >> 4;
  const int m0 = blockIdx.y * 64, n0 = blockIdx.x * 128;
  const int wm = (wave >> 1) * 32, wn = (wave & 1) * 64;

  f4v acc[2][4] = {};

  const int srow = lane >> 2;
  const int scol = (lane & 3) * 8;

  for (int k0 = 0; k0 < K; k0 += 32) {
    gl_lds16(A + (size_t)(m0 + wave * 16 + srow) * K + k0 + scol,
             &As[(wave * 16) * 32]);
#pragma unroll
    for (int p = 0; p < 2; ++p) {
      int r = p * 64 + wave * 16 + srow;
      gl_lds16(BT + (size_t)(n0 + r) * K + k0 + scol,
               &Bs[(p * 64 + wave * 16) * 32]);
    }
    __syncthreads();
    bf8v a[2], b[4];
#pragma unroll
    for (int i = 0; i < 2; ++i)
      a[i] = *(const bf8v*)&As[(wm + i * 16 + lo) * 32 + hi * 8];
#pragma unroll
    for (int j = 0; j < 4; ++j)
      b[j] = *(const bf8v*)&Bs[(wn + j * 16 + lo) * 32 + hi * 8];
#pragma unroll
    for (int i = 0; i < 2; ++i)
#pragma unroll
      for (int j = 0; j < 4; ++j)
        acc[i][j] = __builtin_amdgcn_mfma_f32_16x16x32_bf16(a[i], b[j], acc[i][j], 0, 0, 0);
    __syncthreads();
  }

#pragma unroll
  for (int i = 0; i < 2; ++i) {
#pragma unroll
    for (int r = 0; r < 4; ++r) {
      int row = m0 + wm + i * 16 + hi * 4 + r;
#pragma unroll
      for (int j = 0; j < 4; ++j) {
        int col = n0 + wn + j * 16 + lo;
        C[(size_t)row * N + col] = acc[i][j][r] + bias[col];
      }
    }
  }
}

// ---------------- flash attention v5 ----------------
// Changes vs v4 (latency-bound fixes; MfmaUtil 27% / VALUBusy 40% / both pipes idle 33%):
//  - T14 async-STAGE: next K/V tile prefetched global->reg during current compute;
//    raw s_barrier + lgkmcnt(0) only (NEVER drain vmcnt in the loop -> loads stay in flight).
//  - row-sum l computed on the MFMA pipe (P frags x all-ones B) instead of 32 VALU adds/iter;
//    also deletes the epilogue shuffle tree (l lands in C/D layout matching O).
//  - T1 XCD swizzle: all 16 q-blocks of one (b,h) -> same XCD (KV fits 4MB L2).
//  - T5 s_setprio(1) around MFMA clusters.
//  - QK^T restructured ct-outer (s-frags live 8 VGPR instead of 32) to fit prefetch regs <=128.
#define FSTR 72   // LDS row stride (shorts): 64 payload + 8 pad

__global__ __launch_bounds__(256, 4) void flash_attn(
    const unsigned short* __restrict__ qkv,
    const unsigned short* __restrict__ vtg,
    unsigned short* __restrict__ y) {
  __shared__ __align__(16) unsigned short Ps[128 * FSTR];  // Q stage, then P tile [q][key]
  __shared__ __align__(16) unsigned short Kt[64 * FSTR];   // K tile [key][d]
  __shared__ __align__(16) unsigned short Vt[64 * FSTR];   // V^T tile [d][key]
  const int tid = threadIdx.x;
  const int wave = tid >> 6, lane = tid & 63;
  const int lo = lane & 15, hi = lane >> 4;

  // XCD-aware bijective swizzle (1024 blocks % 8 == 0): consecutive hardware ids
  // (round-robin over XCDs) map to different (b,h) groups; each XCD owns 8 whole
  // (b,h) groups = ~4MB of K/V -> L2-resident re-reads for the 16 q-blocks.
  const int lin = (((blockIdx.z << 4) | blockIdx.y) << 4) | blockIdx.x;
  const int swz = (lin & 7) * 128 + (lin >> 3);
  const int q0 = (swz & 15) << 7;
  const int h  = (swz >> 4) & 15;
  const int b  = swz >> 8;

  const size_t base = (size_t)b * 2048 * 3072;
  const int qoff = h * 64, koff = 1024 + h * 64;
  const unsigned short* vsrc = vtg + (size_t)(b * 16 + h) * 64 * 2048;

  // ---- K/V staging: reg-held prefetch (issue early / ds_write late)
  const int m_st = tid >> 3, c_st = tid & 7;     // each thread: rows m_st,m_st+32, 16B chunk c_st
  const unsigned short* kg = qkv + base + koff;
  float4 rk0, rk1, rv0, rv1;
  auto kv_load = [&](int kt) {
    const int mb = kt * 64;
    rk0 = *(const float4*)(kg + (size_t)(mb + m_st) * 3072 + c_st * 8);
    rk1 = *(const float4*)(kg + (size_t)(mb + m_st + 32) * 3072 + c_st * 8);
    rv0 = *(const float4*)(vsrc + (size_t)m_st * 2048 + mb + c_st * 8);
    rv1 = *(const float4*)(vsrc + (size_t)(m_st + 32) * 2048 + mb + c_st * 8);
  };
  auto kv_write = [&]() {
    *(float4*)&Kt[m_st * FSTR + c_st * 8] = rk0;
    *(float4*)&Kt[(m_st + 32) * FSTR + c_st * 8] = rk1;
    *(float4*)&Vt[m_st * FSTR + c_st * 8] = rv0;
    *(float4*)&Vt[(m_st + 32) * FSTR + c_st * 8] = rv1;
  };

  kv_load(0);  // in flight under the Q stage + prologue barrier

  // ---- stage Q~ into Ps region [128][FSTR]
#pragma unroll
  for (int i = 0; i < 4; ++i) {
    int cid = i * 256 + tid;
    int m = cid >> 3, c = cid & 7;
    *(float4*)&Ps[m * FSTR + c * 8] =
        *(const float4*)(qkv + base + (size_t)(q0 + m) * 3072 + qoff + c * 8);
  }
  __syncthreads();
  // preload Q^T B-operand frags (wave-local rows; P-writes later clobber only our own
  // rows, and those writes are data-dependent on these reads -> no extra barrier needed)
  bf8v bq[2][2];  // [qt][ks]
#pragma unroll
  for (int qt = 0; qt < 2; ++qt)
#pragma unroll
    for (int ks = 0; ks < 2; ++ks)
      bq[qt][ks] = *(const bf8v*)&Ps[(wave * 32 + qt * 16 + lo) * FSTR + ks * 32 + hi * 8];

  f4v O[2][4] = {};       // [qt][dt]; C/D: row=q-in-tile, col=d-in-tile
  f4v acc_l[2] = {};      // row-sums via MFMA x ones; acc_l[qt][r] = l(q = hi*4+r)
  union { bf8v v; unsigned short u[8]; } onesu;
#pragma unroll
  for (int i = 0; i < 8; ++i) onesu.u[i] = 0x3F80;  // bf16 1.0
  const bf8v ones = onesu.v;

  for (int kt = 0; kt < 32; ++kt) {
    // barrier1: previous tile's Kt/Vt reads complete (lgkmcnt drained before each MFMA use)
    asm volatile("" ::: "memory");
    __builtin_amdgcn_s_barrier();
    asm volatile("" ::: "memory");
    kv_write();                       // vmcnt wait here is counted: only this tile's loads
    if (kt < 31) kv_load(kt + 1);     // issue next tile; stays in flight across barriers
    asm volatile("s_waitcnt lgkmcnt(0)" ::: "memory");
    __builtin_amdgcn_s_barrier();     // barrier2: Kt/Vt(kt) visible to all waves
    asm volatile("" ::: "memory");

    // ---- S^T = K . Q~^T, ct-outer: softmax each 16-key strip as it finishes
#pragma unroll
    for (int ct = 0; ct < 4; ++ct) {
      f4v s0 = {}, s1 = {};
      __builtin_amdgcn_s_setprio(1);
#pragma unroll
      for (int ks = 0; ks < 2; ++ks) {
        bf8v ak = *(const bf8v*)&Kt[(ct * 16 + lo) * FSTR + ks * 32 + hi * 8];
        s0 = __builtin_amdgcn_mfma_f32_16x16x32_bf16(ak, bq[0][ks], s0, 0, 0, 0);
        s1 = __builtin_amdgcn_mfma_f32_16x16x32_bf16(ak, bq[1][ks], s1, 0, 0, 0);
      }
      __builtin_amdgcn_s_setprio(0);
      {
        float p0 = exp2_hw(s0[0]), p1 = exp2_hw(s0[1]);
        float p2 = exp2_hw(s0[2]), p3 = exp2_hw(s0[3]);
        uint2 w; w.x = pk2bf(p0, p1); w.y = pk2bf(p2, p3);
        *(uint2*)&Ps[(wave * 32 + lo) * FSTR + ct * 16 + hi * 4] = w;
      }
      {
        float p0 = exp2_hw(s1[0]), p1 = exp2_hw(s1[1]);
        float p2 = exp2_hw(s1[2]), p3 = exp2_hw(s1[3]);
        uint2 w; w.x = pk2bf(p0, p1); w.y = pk2bf(p2, p3);
        *(uint2*)&Ps[(wave * 32 + 16 + lo) * FSTR + ct * 16 + hi * 4] = w;
      }
    }

    // ---- O += P.V ; l += P.1  (row-sum on the MFMA pipe, frees VALU)
#pragma unroll
    for (int ks = 0; ks < 2; ++ks) {
      bf8v ap0 = *(const bf8v*)&Ps[(wave * 32 + lo) * FSTR + ks * 32 + hi * 8];
      bf8v ap1 = *(const bf8v*)&Ps[(wave * 32 + 16 + lo) * FSTR + ks * 32 + hi * 8];
      __builtin_amdgcn_s_setprio(1);
      acc_l[0] = __builtin_amdgcn_mfma_f32_16x16x32_bf16(ap0, ones, acc_l[0], 0, 0, 0);
      acc_l[1] = __builtin_amdgcn_mfma_f32_16x16x32_bf16(ap1, ones, acc_l[1], 0, 0, 0);
#pragma unroll
      for (int dt = 0; dt < 4; ++dt) {
        bf8v bv = *(const bf8v*)&Vt[(dt * 16 + lo) * FSTR + ks * 32 + hi * 8];
        O[0][dt] = __builtin_amdgcn_mfma_f32_16x16x32_bf16(ap0, bv, O[0][dt], 0, 0, 0);
        O[1][dt] = __builtin_amdgcn_mfma_f32_16x16x32_bf16(ap1, bv, O[1][dt], 0, 0, 0);
      }
      __builtin_amdgcn_s_setprio(0);
    }
  }

  // epilogue: acc_l[qt][r] is already the row-sum for q-in-tile = hi*4+r (same C/D
  // layout as O) -> no cross-lane reduction needed
#pragma unroll
  for (int qt = 0; qt < 2; ++qt) {
#pragma unroll
    for (int r = 0; r < 4; ++r) {
      float inv = 1.f / acc_l[qt][r];
      int row = q0 + wave * 32 + qt * 16 + hi * 4 + r;
      size_t orow = ((size_t)b * 2048 + row) * 1024 + h * 64;
#pragma unroll
      for (int dt = 0; dt < 4; ++dt)
        y[orow + dt * 16 + lo] = f2bf(O[qt][dt][r] * inv);
    }
  }
}

// ---------------- launch ----------------
extern "C" void kernel_launch(void* const* d_in, const int* in_sizes, int n_in,
                              void* d_out, int out_size, void* d_ws, size_t ws_size,
                              hipStream_t stream) {
  (void)in_sizes; (void)n_in; (void)out_size; (void)ws_size;
  const float* x     = (const float*)d_in[0];
  const float* w_in  = (const float*)d_in[1];
  const float* b_in  = (const float*)d_in[2];
  const float* w_out = (const float*)d_in[3];
  const float* b_out = (const float*)d_in[4];

  // workspace layout (bf16 elements): vtg aliases xb (xb dead after gemm1)
  unsigned short* xb  = (unsigned short*)d_ws;          // 8192x1024 (later: vtg 64x64x2048)
  unsigned short* wiT = xb  + (size_t)8192 * 1024;      // 3072x1024 (w_in^T)
  unsigned short* woT = wiT + (size_t)3072 * 1024;      // 1024x1024 (w_out^T)
  unsigned short* qkv = woT + (size_t)1024 * 1024;      // 8192x3072
  unsigned short* yb  = qkv + (size_t)8192 * 3072;      // 8192x1024
  unsigned short* vtg = xb;                             // alias: 64*64*2048 == 8192*1024

  cast_bf16_kernel<<<8192, 256, 0, stream>>>(x, xb);
  transpose_w_kernel<<<dim3(128, 32), dim3(32, 8), 0, stream>>>(w_in, w_out, wiT, woT);

  // qkv = x @ w_in + b_in; Q columns (<1024) scaled by log2(e) for exp2 softmax
  gemm_bt<<<dim3(24, 64), 256, 0, stream>>>(xb, wiT, b_in, qkv, 8192, 3072, 1024,
                                            1024, L2E);
  // vtg[b][h][d][n] = V^T  (xb is dead now; reuse its space)
  transpose_v_kernel<<<dim3(64, 2, 64), dim3(32, 8), 0, stream>>>(qkv, vtg);
  // attention -> yb
  flash_attn<<<dim3(16, 16, 4), 256, 0, stream>>>(qkv, vtg, yb);
  // out = yb @ w_out + b_out  (M=8192, N=1024, K=1024), fp32 out
  gemm_bt_sm<<<dim3(8, 128), 256, 0, stream>>>(yb, woT, b_out, (float*)d_out,
                                               8192, 1024, 1024);
}

// Round 2
// 303.194 us; speedup vs baseline: 1.0076x; 1.0020x over previous
//
#include <hip/hip_runtime.h>
#include <hip/hip_bf16.h>
#include <stdint.h>

typedef __attribute__((ext_vector_type(8))) __bf16 bf8v;   // MFMA A/B frag: 8 bf16 = 4 VGPR
typedef __attribute__((ext_vector_type(4))) float f4v;     // MFMA C/D frag

#define L2E 1.44269504088896f

// fp32 -> bf16 round-to-nearest-even (bit pattern as ushort)
__device__ __forceinline__ unsigned short f2bf(float f) {
  union { float f; unsigned u; } v; v.f = f;
  unsigned r = v.u + 0x7fffu + ((v.u >> 16) & 1u);
  return (unsigned short)(r >> 16);
}

// pack two fp32 -> dword of two RNE bf16 (low = f0), HW v_cvt_pk_bf16_f32 path
__device__ __forceinline__ unsigned pk2bf(float f0, float f1) {
  union { __hip_bfloat162 h; unsigned u; } c;
  c.h = __float22bfloat162_rn(make_float2(f0, f1));
  return c.u;
}

// 2^x via v_exp_f32 (native semantic of the HW transcendental)
__device__ __forceinline__ float exp2_hw(float x) {
  return __builtin_amdgcn_exp2f(x);
}

// async global->LDS, 16B per lane; LDS dest = wave-uniform base + lane*16
__device__ __forceinline__ void gl_lds16(const void* g, void* l) {
  __builtin_amdgcn_global_load_lds(
      (__attribute__((address_space(1))) void*)(g),
      (__attribute__((address_space(3))) void*)(l), 16, 0, 0);
}

// ---------------- elementwise cast ----------------
__global__ void cast_bf16_kernel(const float* __restrict__ in,
                                 unsigned short* __restrict__ out) {
  int i = blockIdx.x * 256 + threadIdx.x;
  float4 v = ((const float4*)in)[i];
  ushort4 o;
  o.x = f2bf(v.x); o.y = f2bf(v.y); o.z = f2bf(v.z); o.w = f2bf(v.w);
  ((ushort4*)out)[i] = o;
}

// ---------------- fused weight transpose+cast: w_in (1024x3072) and w_out (1024x1024) ----------------
__global__ void transpose_w_kernel(const float* __restrict__ w_in,
                                   const float* __restrict__ w_out,
                                   unsigned short* __restrict__ wiT,
                                   unsigned short* __restrict__ woT) {
  __shared__ float tile[32][33];
  int bx = blockIdx.x;
  const float* in; unsigned short* out; int C, c0;
  if (bx < 96) { in = w_in;  out = wiT; C = 3072; c0 = bx * 32; }
  else         { in = w_out; out = woT; C = 1024; c0 = (bx - 96) * 32; }
  int r0 = blockIdx.y * 32;
  int tx = threadIdx.x, ty = threadIdx.y;
#pragma unroll
  for (int j = 0; j < 4; ++j)
    tile[ty + 8 * j][tx] = in[(size_t)(r0 + ty + 8 * j) * C + c0 + tx];
  __syncthreads();
#pragma unroll
  for (int j = 0; j < 4; ++j)
    out[(size_t)(c0 + ty + 8 * j) * 1024 + r0 + tx] = f2bf(tile[tx][ty + 8 * j]);
}

// ---------------- V transpose: qkv v-part -> vtg[b][h][d][n] (bf16) ----------------
__global__ void transpose_v_kernel(const unsigned short* __restrict__ qkv,
                                   unsigned short* __restrict__ vtg) {
  __shared__ unsigned short tile[32][33];
  int bh = blockIdx.z;            // b*16 + h
  int d0 = blockIdx.y * 32;       // 0 or 32
  int n0 = blockIdx.x * 32;
  int b = bh >> 4, h = bh & 15;
  int tx = threadIdx.x, ty = threadIdx.y;
  const unsigned short* src = qkv + (size_t)b * 2048 * 3072 + 2048 + h * 64 + d0;
#pragma unroll
  for (int j = 0; j < 4; ++j)
    tile[ty + 8 * j][tx] = src[(size_t)(n0 + ty + 8 * j) * 3072 + tx];
  __syncthreads();
  unsigned short* dst = vtg + ((size_t)bh * 64) * 2048;
#pragma unroll
  for (int j = 0; j < 4; ++j)
    dst[(size_t)(d0 + ty + 8 * j) * 2048 + n0 + tx] = tile[tx][ty + 8 * j];
}

// ---------------- GEMM1 v2: 256x256 tile, BK=64, deep pipeline ----------------
// C = A(MxK)*BT(NxK)^T + bias, bf16 out; cols < scale_ncols scaled.
// Structure (T2+T3+T4+T5, derived from the 256^2 template):
//  - 512 threads = 8 waves (2M x 4N), per-wave output 128x64 = acc[8][4].
//  - LDS 128 KiB: A/B double-buffered K-tiles [2][256 rows][64 k] bf16.
//  - Prefetch: 8 gl_lds (full next tile) issued in a burst right after the
//    tile-start barrier; s_waitcnt vmcnt(8) = counted, never drains to 0.
//  - Raw s_barrier (x2 per K-tile) only; no __syncthreads (no vmcnt(0) drain).
//  - Swizzle: col ^= 16 elems when (row&4), applied to BOTH the per-lane global
//    source of gl_lds and the ds_read addresses (same involution both sides).
__global__ __launch_bounds__(512, 2) void gemm_bt256(
    const unsigned short* __restrict__ A,
    const unsigned short* __restrict__ BT,
    const float* __restrict__ bias,
    unsigned short* __restrict__ C,
    int N, int K, int nbx, int scale_ncols, float scale) {
  __shared__ __align__(16) unsigned short As[2][256 * 64];
  __shared__ __align__(16) unsigned short Bs[2][256 * 64];
  const int tid = threadIdx.x;
  const int wave = tid >> 6, lane = tid & 63;
  const int lo = lane & 15, hi = lane >> 4;
  const int wm = wave >> 2, wn = wave & 3;

  // XCD-aware swizzle (grid %8 == 0): each XCD owns nwg/8 consecutive tiles
  const int nwg = gridDim.x;
  const int cpx = nwg >> 3;
  const int s = (blockIdx.x & 7) * cpx + (blockIdx.x >> 3);
  const int by = s / nbx, bx = s - by * nbx;
  const int m0 = by * 256, n0 = bx * 256;

  // staging: lane -> (row-in-8, 16B chunk); source col pre-swizzled (row&4 <=> lane&32)
  const int srow = lane >> 3;
  const int scol = ((lane & 7) * 8) ^ ((lane >> 1) & 16);
  const unsigned short* gA = A + (size_t)(m0 + wave * 8 + srow) * K + scol;
  const unsigned short* gB = BT + (size_t)(n0 + wave * 8 + srow) * K + scol;

  // ds_read cols (elements), same involution: row&4 == lo&4 (row base ≡ 0 mod 8)
  const int colsw0 = (hi * 8) ^ ((lo & 4) << 2);
  const int colsw1 = (32 + hi * 8) ^ ((lo & 4) << 2);
  const int rA = wm * 128 + lo;   // + fm*16
  const int rB = wn * 64 + lo;    // + fn*16

  f4v acc[8][4] = {};
  const int nt = K >> 6;

  // prologue: stage tile 0 into parity 0
#pragma unroll
  for (int j = 0; j < 4; ++j) {
    gl_lds16(gA + (size_t)(j * 64) * K, &As[0][(j * 64 + wave * 8) * 64]);
    gl_lds16(gB + (size_t)(j * 64) * K, &Bs[0][(j * 64 + wave * 8) * 64]);
  }

  for (int t = 0; t < nt; ++t) {
    const int c = t & 1;
    // barrier1: tile t-1's readers of parity c^1 are done -> safe to overwrite
    __builtin_amdgcn_s_barrier();
    __builtin_amdgcn_sched_barrier(0);
    if (t + 1 < nt) {
      const unsigned short* gA1 = gA + (size_t)(t + 1) * 64;
      const unsigned short* gB1 = gB + (size_t)(t + 1) * 64;
#pragma unroll
      for (int j = 0; j < 4; ++j) {
        gl_lds16(gA1 + (size_t)(j * 64) * K, &As[c ^ 1][(j * 64 + wave * 8) * 64]);
        gl_lds16(gB1 + (size_t)(j * 64) * K, &Bs[c ^ 1][(j * 64 + wave * 8) * 64]);
      }
      asm volatile("s_waitcnt vmcnt(8)" ::: "memory");  // tile t landed; t+1 in flight
    } else {
      asm volatile("s_waitcnt vmcnt(0)" ::: "memory");  // final tile: drain
    }
    __builtin_amdgcn_sched_barrier(0);
    __builtin_amdgcn_s_barrier();   // barrier2: all waves' tile-t data visible
    __builtin_amdgcn_sched_barrier(0);

    // B fragments for the whole tile (8 x ds_read_b128)
    bf8v b[4][2];
#pragma unroll
    for (int fn = 0; fn < 4; ++fn) {
      b[fn][0] = *(const bf8v*)&Bs[c][(rB + fn * 16) * 64 + colsw0];
      b[fn][1] = *(const bf8v*)&Bs[c][(rB + fn * 16) * 64 + colsw1];
    }
    // 4 phases: A-quad (4 x ds_read_b128) + 16 MFMA each
#pragma unroll
    for (int p = 0; p < 4; ++p) {
      bf8v a[2][2];
#pragma unroll
      for (int i = 0; i < 2; ++i) {
        a[i][0] = *(const bf8v*)&As[c][(rA + (p * 2 + i) * 16) * 64 + colsw0];
        a[i][1] = *(const bf8v*)&As[c][(rA + (p * 2 + i) * 16) * 64 + colsw1];
      }
      __builtin_amdgcn_s_setprio(1);
#pragma unroll
      for (int ks = 0; ks < 2; ++ks)
#pragma unroll
        for (int i = 0; i < 2; ++i)
#pragma unroll
          for (int fn = 0; fn < 4; ++fn)
            acc[p * 2 + i][fn] = __builtin_amdgcn_mfma_f32_16x16x32_bf16(
                a[i][ks], b[fn][ks], acc[p * 2 + i][fn], 0, 0, 0);
      __builtin_amdgcn_s_setprio(0);
    }
  }

  // epilogue
#pragma unroll
  for (int i = 0; i < 8; ++i) {
#pragma unroll
    for (int r = 0; r < 4; ++r) {
      int row = m0 + wm * 128 + i * 16 + hi * 4 + r;
#pragma unroll
      for (int j = 0; j < 4; ++j) {
        int col = n0 + wn * 64 + j * 16 + lo;
        float v = acc[i][j][r] + bias[col];
        if (col < scale_ncols) v *= scale;
        C[(size_t)row * N + col] = f2bf(v);
      }
    }
  }
}

// ---------------- GEMM2: 64x128 tile, fp32 out (better occupancy at M=8192,N=1024) ----------------
__global__ __launch_bounds__(256, 4) void gemm_bt_sm(
    const unsigned short* __restrict__ A,
    const unsigned short* __restrict__ BT,
    const float* __restrict__ bias,
    float* __restrict__ C,
    int M, int N, int K) {
  __shared__ __align__(16) unsigned short As[64 * 32];   // [m][k]
  __shared__ __align__(16) unsigned short Bs[128 * 32];  // [n][k]
  const int tid = threadIdx.x;
  const int wave = tid >> 6, lane = tid & 63;
  const int lo = lane & 15, hi = lane >> 4;
  const int m0 = blockIdx.y * 64, n0 = blockIdx.x * 128;
  const int wm = (wave >> 1) * 32, wn = (wave & 1) * 64;

  f4v acc[2][4] = {};

  const int srow = lane >> 2;
  const int scol = (lane & 3) * 8;

  for (int k0 = 0; k0 < K; k0 += 32) {
    gl_lds16(A + (size_t)(m0 + wave * 16 + srow) * K + k0 + scol,
             &As[(wave * 16) * 32]);
#pragma unroll
    for (int p = 0; p < 2; ++p) {
      int r = p * 64 + wave * 16 + srow;
      gl_lds16(BT + (size_t)(n0 + r) * K + k0 + scol,
               &Bs[(p * 64 + wave * 16) * 32]);
    }
    __syncthreads();
    bf8v a[2], b[4];
#pragma unroll
    for (int i = 0; i < 2; ++i)
      a[i] = *(const bf8v*)&As[(wm + i * 16 + lo) * 32 + hi * 8];
#pragma unroll
    for (int j = 0; j < 4; ++j)
      b[j] = *(const bf8v*)&Bs[(wn + j * 16 + lo) * 32 + hi * 8];
#pragma unroll
    for (int i = 0; i < 2; ++i)
#pragma unroll
      for (int j = 0; j < 4; ++j)
        acc[i][j] = __builtin_amdgcn_mfma_f32_16x16x32_bf16(a[i], b[j], acc[i][j], 0, 0, 0);
    __syncthreads();
  }

#pragma unroll
  for (int i = 0; i < 2; ++i) {
#pragma unroll
    for (int r = 0; r < 4; ++r) {
      int row = m0 + wm + i * 16 + hi * 4 + r;
#pragma unroll
      for (int j = 0; j < 4; ++j) {
        int col = n0 + wn + j * 16 + lo;
        C[(size_t)row * N + col] = acc[i][j][r] + bias[col];
      }
    }
  }
}

// ---------------- flash attention v5 (unchanged this round) ----------------
#define FSTR 72   // LDS row stride (shorts): 64 payload + 8 pad

__global__ __launch_bounds__(256, 4) void flash_attn(
    const unsigned short* __restrict__ qkv,
    const unsigned short* __restrict__ vtg,
    unsigned short* __restrict__ y) {
  __shared__ __align__(16) unsigned short Ps[128 * FSTR];  // Q stage, then P tile [q][key]
  __shared__ __align__(16) unsigned short Kt[64 * FSTR];   // K tile [key][d]
  __shared__ __align__(16) unsigned short Vt[64 * FSTR];   // V^T tile [d][key]
  const int tid = threadIdx.x;
  const int wave = tid >> 6, lane = tid & 63;
  const int lo = lane & 15, hi = lane >> 4;

  const int lin = (((blockIdx.z << 4) | blockIdx.y) << 4) | blockIdx.x;
  const int swz = (lin & 7) * 128 + (lin >> 3);
  const int q0 = (swz & 15) << 7;
  const int h  = (swz >> 4) & 15;
  const int b  = swz >> 8;

  const size_t base = (size_t)b * 2048 * 3072;
  const int qoff = h * 64, koff = 1024 + h * 64;
  const unsigned short* vsrc = vtg + (size_t)(b * 16 + h) * 64 * 2048;

  // ---- K/V staging: reg-held prefetch (issue early / ds_write late)
  const int m_st = tid >> 3, c_st = tid & 7;
  const unsigned short* kg = qkv + base + koff;
  float4 rk0, rk1, rv0, rv1;
  auto kv_load = [&](int kt) {
    const int mb = kt * 64;
    rk0 = *(const float4*)(kg + (size_t)(mb + m_st) * 3072 + c_st * 8);
    rk1 = *(const float4*)(kg + (size_t)(mb + m_st + 32) * 3072 + c_st * 8);
    rv0 = *(const float4*)(vsrc + (size_t)m_st * 2048 + mb + c_st * 8);
    rv1 = *(const float4*)(vsrc + (size_t)(m_st + 32) * 2048 + mb + c_st * 8);
  };
  auto kv_write = [&]() {
    *(float4*)&Kt[m_st * FSTR + c_st * 8] = rk0;
    *(float4*)&Kt[(m_st + 32) * FSTR + c_st * 8] = rk1;
    *(float4*)&Vt[m_st * FSTR + c_st * 8] = rv0;
    *(float4*)&Vt[(m_st + 32) * FSTR + c_st * 8] = rv1;
  };

  kv_load(0);

  // ---- stage Q~ into Ps region [128][FSTR]
#pragma unroll
  for (int i = 0; i < 4; ++i) {
    int cid = i * 256 + tid;
    int m = cid >> 3, c = cid & 7;
    *(float4*)&Ps[m * FSTR + c * 8] =
        *(const float4*)(qkv + base + (size_t)(q0 + m) * 3072 + qoff + c * 8);
  }
  __syncthreads();
  bf8v bq[2][2];  // [qt][ks]
#pragma unroll
  for (int qt = 0; qt < 2; ++qt)
#pragma unroll
    for (int ks = 0; ks < 2; ++ks)
      bq[qt][ks] = *(const bf8v*)&Ps[(wave * 32 + qt * 16 + lo) * FSTR + ks * 32 + hi * 8];

  f4v O[2][4] = {};
  f4v acc_l[2] = {};
  union { bf8v v; unsigned short u[8]; } onesu;
#pragma unroll
  for (int i = 0; i < 8; ++i) onesu.u[i] = 0x3F80;  // bf16 1.0
  const bf8v ones = onesu.v;

  for (int kt = 0; kt < 32; ++kt) {
    asm volatile("" ::: "memory");
    __builtin_amdgcn_s_barrier();
    asm volatile("" ::: "memory");
    kv_write();
    if (kt < 31) kv_load(kt + 1);
    asm volatile("s_waitcnt lgkmcnt(0)" ::: "memory");
    __builtin_amdgcn_s_barrier();
    asm volatile("" ::: "memory");

#pragma unroll
    for (int ct = 0; ct < 4; ++ct) {
      f4v s0 = {}, s1 = {};
      __builtin_amdgcn_s_setprio(1);
#pragma unroll
      for (int ks = 0; ks < 2; ++ks) {
        bf8v ak = *(const bf8v*)&Kt[(ct * 16 + lo) * FSTR + ks * 32 + hi * 8];
        s0 = __builtin_amdgcn_mfma_f32_16x16x32_bf16(ak, bq[0][ks], s0, 0, 0, 0);
        s1 = __builtin_amdgcn_mfma_f32_16x16x32_bf16(ak, bq[1][ks], s1, 0, 0, 0);
      }
      __builtin_amdgcn_s_setprio(0);
      {
        float p0 = exp2_hw(s0[0]), p1 = exp2_hw(s0[1]);
        float p2 = exp2_hw(s0[2]), p3 = exp2_hw(s0[3]);
        uint2 w; w.x = pk2bf(p0, p1); w.y = pk2bf(p2, p3);
        *(uint2*)&Ps[(wave * 32 + lo) * FSTR + ct * 16 + hi * 4] = w;
      }
      {
        float p0 = exp2_hw(s1[0]), p1 = exp2_hw(s1[1]);
        float p2 = exp2_hw(s1[2]), p3 = exp2_hw(s1[3]);
        uint2 w; w.x = pk2bf(p0, p1); w.y = pk2bf(p2, p3);
        *(uint2*)&Ps[(wave * 32 + 16 + lo) * FSTR + ct * 16 + hi * 4] = w;
      }
    }

#pragma unroll
    for (int ks = 0; ks < 2; ++ks) {
      bf8v ap0 = *(const bf8v*)&Ps[(wave * 32 + lo) * FSTR + ks * 32 + hi * 8];
      bf8v ap1 = *(const bf8v*)&Ps[(wave * 32 + 16 + lo) * FSTR + ks * 32 + hi * 8];
      __builtin_amdgcn_s_setprio(1);
      acc_l[0] = __builtin_amdgcn_mfma_f32_16x16x32_bf16(ap0, ones, acc_l[0], 0, 0, 0);
      acc_l[1] = __builtin_amdgcn_mfma_f32_16x16x32_bf16(ap1, ones, acc_l[1], 0, 0, 0);
#pragma unroll
      for (int dt = 0; dt < 4; ++dt) {
        bf8v bv = *(const bf8v*)&Vt[(dt * 16 + lo) * FSTR + ks * 32 + hi * 8];
        O[0][dt] = __builtin_amdgcn_mfma_f32_16x16x32_bf16(ap0, bv, O[0][dt], 0, 0, 0);
        O[1][dt] = __builtin_amdgcn_mfma_f32_16x16x32_bf16(ap1, bv, O[1][dt], 0, 0, 0);
      }
      __builtin_amdgcn_s_setprio(0);
    }
  }

#pragma unroll
  for (int qt = 0; qt < 2; ++qt) {
#pragma unroll
    for (int r = 0; r < 4; ++r) {
      float inv = 1.f / acc_l[qt][r];
      int row = q0 + wave * 32 + qt * 16 + hi * 4 + r;
      size_t orow = ((size_t)b * 2048 + row) * 1024 + h * 64;
#pragma unroll
      for (int dt = 0; dt < 4; ++dt)
        y[orow + dt * 16 + lo] = f2bf(O[qt][dt][r] * inv);
    }
  }
}

// ---------------- launch ----------------
extern "C" void kernel_launch(void* const* d_in, const int* in_sizes, int n_in,
                              void* d_out, int out_size, void* d_ws, size_t ws_size,
                              hipStream_t stream) {
  (void)in_sizes; (void)n_in; (void)out_size; (void)ws_size;
  const float* x     = (const float*)d_in[0];
  const float* w_in  = (const float*)d_in[1];
  const float* b_in  = (const float*)d_in[2];
  const float* w_out = (const float*)d_in[3];
  const float* b_out = (const float*)d_in[4];

  // workspace layout (bf16 elements): vtg aliases xb (xb dead after gemm1)
  unsigned short* xb  = (unsigned short*)d_ws;          // 8192x1024 (later: vtg 64x64x2048)
  unsigned short* wiT = xb  + (size_t)8192 * 1024;      // 3072x1024 (w_in^T)
  unsigned short* woT = wiT + (size_t)3072 * 1024;      // 1024x1024 (w_out^T)
  unsigned short* qkv = woT + (size_t)1024 * 1024;      // 8192x3072
  unsigned short* yb  = qkv + (size_t)8192 * 3072;      // 8192x1024
  unsigned short* vtg = xb;                             // alias: 64*64*2048 == 8192*1024

  cast_bf16_kernel<<<8192, 256, 0, stream>>>(x, xb);
  transpose_w_kernel<<<dim3(128, 32), dim3(32, 8), 0, stream>>>(w_in, w_out, wiT, woT);

  // qkv = x @ w_in + b_in; Q columns (<1024) scaled by log2(e) for exp2 softmax
  // 256x256 tiles: grid 32x12 = 384 blocks (384 % 8 == 0 for the XCD swizzle)
  gemm_bt256<<<384, 512, 0, stream>>>(xb, wiT, b_in, qkv, 3072, 1024, 12, 1024, L2E);
  // vtg[b][h][d][n] = V^T  (xb is dead now; reuse its space)
  transpose_v_kernel<<<dim3(64, 2, 64), dim3(32, 8), 0, stream>>>(qkv, vtg);
  // attention -> yb
  flash_attn<<<dim3(16, 16, 4), 256, 0, stream>>>(qkv, vtg, yb);
  // out = yb @ w_out + b_out  (M=8192, N=1024, K=1024), fp32 out
  gemm_bt_sm<<<dim3(8, 128), 256, 0, stream>>>(yb, woT, b_out, (float*)d_out,
                                               8192, 1024, 1024);
}

// Round 3
// 294.424 us; speedup vs baseline: 1.0376x; 1.0298x over previous
//
#include <hip/hip_runtime.h>
#include <hip/hip_bf16.h>
#include <stdint.h>

typedef __attribute__((ext_vector_type(8))) __bf16 bf8v;   // MFMA A/B frag: 8 bf16 = 4 VGPR
typedef __attribute__((ext_vector_type(4))) float f4v;     // MFMA C/D frag

#define L2E 1.44269504088896f

// fp32 -> bf16 round-to-nearest-even (bit pattern as ushort)
__device__ __forceinline__ unsigned short f2bf(float f) {
  union { float f; unsigned u; } v; v.f = f;
  unsigned r = v.u + 0x7fffu + ((v.u >> 16) & 1u);
  return (unsigned short)(r >> 16);
}

// pack two fp32 -> dword of two RNE bf16 (low = f0), HW v_cvt_pk_bf16_f32 path
__device__ __forceinline__ unsigned pk2bf(float f0, float f1) {
  union { __hip_bfloat162 h; unsigned u; } c;
  c.h = __float22bfloat162_rn(make_float2(f0, f1));
  return c.u;
}

// 2^x via v_exp_f32 (native semantic of the HW transcendental)
__device__ __forceinline__ float exp2_hw(float x) {
  return __builtin_amdgcn_exp2f(x);
}

// async global->LDS, 16B per lane; LDS dest = wave-uniform base + lane*16
__device__ __forceinline__ void gl_lds16(const void* g, void* l) {
  __builtin_amdgcn_global_load_lds(
      (__attribute__((address_space(1))) void*)(g),
      (__attribute__((address_space(3))) void*)(l), 16, 0, 0);
}

// ---------------- fused prep: cast x -> bf16  +  weight transpose/cast ----------------
// blocks [0, 8192): cast x (float4 per thread). blocks [8192, 12288): transpose w_in/w_out.
__global__ void prep_kernel(const float* __restrict__ x,
                            const float* __restrict__ w_in,
                            const float* __restrict__ w_out,
                            unsigned short* __restrict__ xb,
                            unsigned short* __restrict__ wiT,
                            unsigned short* __restrict__ woT) {
  __shared__ float tile[32][33];
  int bx = blockIdx.x;
  if (bx < 8192) {
    int i = bx * 256 + threadIdx.x;
    float4 v = ((const float4*)x)[i];
    ushort4 o;
    o.x = f2bf(v.x); o.y = f2bf(v.y); o.z = f2bf(v.z); o.w = f2bf(v.w);
    ((ushort4*)xb)[i] = o;
    return;
  }
  int idx = bx - 8192;              // 0..4095 -> (128 x, 32 y)
  int bxx = idx & 127, byy = idx >> 7;
  const float* in; unsigned short* out; int C, c0;
  if (bxx < 96) { in = w_in;  out = wiT; C = 3072; c0 = bxx * 32; }
  else          { in = w_out; out = woT; C = 1024; c0 = (bxx - 96) * 32; }
  int r0 = byy * 32;
  int tx = threadIdx.x & 31, ty = threadIdx.x >> 5;
#pragma unroll
  for (int j = 0; j < 4; ++j)
    tile[ty + 8 * j][tx] = in[(size_t)(r0 + ty + 8 * j) * C + c0 + tx];
  __syncthreads();
#pragma unroll
  for (int j = 0; j < 4; ++j)
    out[(size_t)(c0 + ty + 8 * j) * 1024 + r0 + tx] = f2bf(tile[tx][ty + 8 * j]);
}

// ---------------- V transpose: qkv v-part -> vtg[b][h][d][n] (bf16) ----------------
__global__ void transpose_v_kernel(const unsigned short* __restrict__ qkv,
                                   unsigned short* __restrict__ vtg) {
  __shared__ unsigned short tile[32][33];
  int bh = blockIdx.z;            // b*16 + h
  int d0 = blockIdx.y * 32;       // 0 or 32
  int n0 = blockIdx.x * 32;
  int b = bh >> 4, h = bh & 15;
  int tx = threadIdx.x, ty = threadIdx.y;
  const unsigned short* src = qkv + (size_t)b * 2048 * 3072 + 2048 + h * 64 + d0;
#pragma unroll
  for (int j = 0; j < 4; ++j)
    tile[ty + 8 * j][tx] = src[(size_t)(n0 + ty + 8 * j) * 3072 + tx];
  __syncthreads();
  unsigned short* dst = vtg + ((size_t)bh * 64) * 2048;
#pragma unroll
  for (int j = 0; j < 4; ++j)
    dst[(size_t)(d0 + ty + 8 * j) * 2048 + n0 + tx] = tile[tx][ty + 8 * j];
}

// ---------------- GEMM1: 256x256 tile, BK=64, deep pipeline (unchanged) ----------------
__global__ __launch_bounds__(512, 2) void gemm_bt256(
    const unsigned short* __restrict__ A,
    const unsigned short* __restrict__ BT,
    const float* __restrict__ bias,
    unsigned short* __restrict__ C,
    int N, int K, int nbx, int scale_ncols, float scale) {
  __shared__ __align__(16) unsigned short As[2][256 * 64];
  __shared__ __align__(16) unsigned short Bs[2][256 * 64];
  const int tid = threadIdx.x;
  const int wave = tid >> 6, lane = tid & 63;
  const int lo = lane & 15, hi = lane >> 4;
  const int wm = wave >> 2, wn = wave & 3;

  const int nwg = gridDim.x;
  const int cpx = nwg >> 3;
  const int s = (blockIdx.x & 7) * cpx + (blockIdx.x >> 3);
  const int by = s / nbx, bx = s - by * nbx;
  const int m0 = by * 256, n0 = bx * 256;

  const int srow = lane >> 3;
  const int scol = ((lane & 7) * 8) ^ ((lane >> 1) & 16);
  const unsigned short* gA = A + (size_t)(m0 + wave * 8 + srow) * K + scol;
  const unsigned short* gB = BT + (size_t)(n0 + wave * 8 + srow) * K + scol;

  const int colsw0 = (hi * 8) ^ ((lo & 4) << 2);
  const int colsw1 = (32 + hi * 8) ^ ((lo & 4) << 2);
  const int rA = wm * 128 + lo;
  const int rB = wn * 64 + lo;

  f4v acc[8][4] = {};
  const int nt = K >> 6;

#pragma unroll
  for (int j = 0; j < 4; ++j) {
    gl_lds16(gA + (size_t)(j * 64) * K, &As[0][(j * 64 + wave * 8) * 64]);
    gl_lds16(gB + (size_t)(j * 64) * K, &Bs[0][(j * 64 + wave * 8) * 64]);
  }

  for (int t = 0; t < nt; ++t) {
    const int c = t & 1;
    __builtin_amdgcn_s_barrier();
    __builtin_amdgcn_sched_barrier(0);
    if (t + 1 < nt) {
      const unsigned short* gA1 = gA + (size_t)(t + 1) * 64;
      const unsigned short* gB1 = gB + (size_t)(t + 1) * 64;
#pragma unroll
      for (int j = 0; j < 4; ++j) {
        gl_lds16(gA1 + (size_t)(j * 64) * K, &As[c ^ 1][(j * 64 + wave * 8) * 64]);
        gl_lds16(gB1 + (size_t)(j * 64) * K, &Bs[c ^ 1][(j * 64 + wave * 8) * 64]);
      }
      asm volatile("s_waitcnt vmcnt(8)" ::: "memory");
    } else {
      asm volatile("s_waitcnt vmcnt(0)" ::: "memory");
    }
    __builtin_amdgcn_sched_barrier(0);
    __builtin_amdgcn_s_barrier();
    __builtin_amdgcn_sched_barrier(0);

    bf8v b[4][2];
#pragma unroll
    for (int fn = 0; fn < 4; ++fn) {
      b[fn][0] = *(const bf8v*)&Bs[c][(rB + fn * 16) * 64 + colsw0];
      b[fn][1] = *(const bf8v*)&Bs[c][(rB + fn * 16) * 64 + colsw1];
    }
#pragma unroll
    for (int p = 0; p < 4; ++p) {
      bf8v a[2][2];
#pragma unroll
      for (int i = 0; i < 2; ++i) {
        a[i][0] = *(const bf8v*)&As[c][(rA + (p * 2 + i) * 16) * 64 + colsw0];
        a[i][1] = *(const bf8v*)&As[c][(rA + (p * 2 + i) * 16) * 64 + colsw1];
      }
      __builtin_amdgcn_s_setprio(1);
#pragma unroll
      for (int ks = 0; ks < 2; ++ks)
#pragma unroll
        for (int i = 0; i < 2; ++i)
#pragma unroll
          for (int fn = 0; fn < 4; ++fn)
            acc[p * 2 + i][fn] = __builtin_amdgcn_mfma_f32_16x16x32_bf16(
                a[i][ks], b[fn][ks], acc[p * 2 + i][fn], 0, 0, 0);
      __builtin_amdgcn_s_setprio(0);
    }
  }

#pragma unroll
  for (int i = 0; i < 8; ++i) {
#pragma unroll
    for (int r = 0; r < 4; ++r) {
      int row = m0 + wm * 128 + i * 16 + hi * 4 + r;
#pragma unroll
      for (int j = 0; j < 4; ++j) {
        int col = n0 + wn * 64 + j * 16 + lo;
        float v = acc[i][j][r] + bias[col];
        if (col < scale_ncols) v *= scale;
        C[(size_t)row * N + col] = f2bf(v);
      }
    }
  }
}

// ---------------- GEMM2: 64x128 tile, fp32 out (unchanged) ----------------
__global__ __launch_bounds__(256, 4) void gemm_bt_sm(
    const unsigned short* __restrict__ A,
    const unsigned short* __restrict__ BT,
    const float* __restrict__ bias,
    float* __restrict__ C,
    int M, int N, int K) {
  __shared__ __align__(16) unsigned short As[64 * 32];   // [m][k]
  __shared__ __align__(16) unsigned short Bs[128 * 32];  // [n][k]
  const int tid = threadIdx.x;
  const int wave = tid >> 6, lane = tid & 63;
  const int lo = lane & 15, hi = lane >> 4;
  const int m0 = blockIdx.y * 64, n0 = blockIdx.x * 128;
  const int wm = (wave >> 1) * 32, wn = (wave & 1) * 64;

  f4v acc[2][4] = {};

  const int srow = lane >> 2;
  const int scol = (lane & 3) * 8;

  for (int k0 = 0; k0 < K; k0 += 32) {
    gl_lds16(A + (size_t)(m0 + wave * 16 + srow) * K + k0 + scol,
             &As[(wave * 16) * 32]);
#pragma unroll
    for (int p = 0; p < 2; ++p) {
      int r = p * 64 + wave * 16 + srow;
      gl_lds16(BT + (size_t)(n0 + r) * K + k0 + scol,
               &Bs[(p * 64 + wave * 16) * 32]);
    }
    __syncthreads();
    bf8v a[2], b[4];
#pragma unroll
    for (int i = 0; i < 2; ++i)
      a[i] = *(const bf8v*)&As[(wm + i * 16 + lo) * 32 + hi * 8];
#pragma unroll
    for (int j = 0; j < 4; ++j)
      b[j] = *(const bf8v*)&Bs[(wn + j * 16 + lo) * 32 + hi * 8];
#pragma unroll
    for (int i = 0; i < 2; ++i)
#pragma unroll
      for (int j = 0; j < 4; ++j)
        acc[i][j] = __builtin_amdgcn_mfma_f32_16x16x32_bf16(a[i], b[j], acc[i][j], 0, 0, 0);
    __syncthreads();
  }

#pragma unroll
  for (int i = 0; i < 2; ++i) {
#pragma unroll
    for (int r = 0; r < 4; ++r) {
      int row = m0 + wm + i * 16 + hi * 4 + r;
#pragma unroll
      for (int j = 0; j < 4; ++j) {
        int col = n0 + wn + j * 16 + lo;
        C[(size_t)row * N + col] = acc[i][j][r] + bias[col];
      }
    }
  }
}

// ---------------- flash attention v6 ----------------
// LDS-throughput fix: per-wave q-rows 32 -> 64 (block = 256 q-rows). K/V tiles are
// re-read in full by every wave, so K/V LDS traffic per output halves; barriers per
// output halve too. Per-CU-kt DS-pipe demand drops ~36% (was ~77% busy = the binder).
// Grid 512, 2 blocks/CU (LDS 54 KiB), all blocks resident in one shot.
#define FSTR 72   // LDS row stride (shorts): 64 payload + 8 pad (rows cycle all 32 banks / 8)

__global__ __launch_bounds__(256, 2) void flash_attn(
    const unsigned short* __restrict__ qkv,
    const unsigned short* __restrict__ vtg,
    unsigned short* __restrict__ y) {
  __shared__ __align__(16) unsigned short Ps[256 * FSTR];  // Q stage, then P tile [q][key]
  __shared__ __align__(16) unsigned short Kt[64 * FSTR];   // K tile [key][d]
  __shared__ __align__(16) unsigned short Vt[64 * FSTR];   // V^T tile [d][key]
  const int tid = threadIdx.x;
  const int wave = tid >> 6, lane = tid & 63;
  const int lo = lane & 15, hi = lane >> 4;

  // XCD swizzle: 512 blocks; XCD c gets swz in [c*64, c*64+64) = one b, 8 heads (~4MB KV -> L2)
  const int lin = blockIdx.x;
  const int swz = (lin & 7) * 64 + (lin >> 3);
  const int q0 = (swz & 7) << 8;        // 8 q-blocks of 256
  const int h  = (swz >> 3) & 15;
  const int b  = swz >> 7;

  const size_t base = (size_t)b * 2048 * 3072;
  const int qoff = h * 64, koff = 1024 + h * 64;
  const unsigned short* vsrc = vtg + (size_t)(b * 16 + h) * 64 * 2048;

  // ---- K/V staging: reg-held prefetch (issue early / ds_write late)
  const int m_st = tid >> 3, c_st = tid & 7;
  const unsigned short* kg = qkv + base + koff;
  float4 rk0, rk1, rv0, rv1;
  auto kv_load = [&](int kt) {
    const int mb = kt * 64;
    rk0 = *(const float4*)(kg + (size_t)(mb + m_st) * 3072 + c_st * 8);
    rk1 = *(const float4*)(kg + (size_t)(mb + m_st + 32) * 3072 + c_st * 8);
    rv0 = *(const float4*)(vsrc + (size_t)m_st * 2048 + mb + c_st * 8);
    rv1 = *(const float4*)(vsrc + (size_t)(m_st + 32) * 2048 + mb + c_st * 8);
  };
  auto kv_write = [&]() {
    *(float4*)&Kt[m_st * FSTR + c_st * 8] = rk0;
    *(float4*)&Kt[(m_st + 32) * FSTR + c_st * 8] = rk1;
    *(float4*)&Vt[m_st * FSTR + c_st * 8] = rv0;
    *(float4*)&Vt[(m_st + 32) * FSTR + c_st * 8] = rv1;
  };

  kv_load(0);

  // ---- stage Q~ into Ps region [256][FSTR]
#pragma unroll
  for (int i = 0; i < 8; ++i) {
    int cid = i * 256 + tid;
    int m = cid >> 3, c = cid & 7;
    *(float4*)&Ps[m * FSTR + c * 8] =
        *(const float4*)(qkv + base + (size_t)(q0 + m) * 3072 + qoff + c * 8);
  }
  __syncthreads();
  // preload Q^T B-operand frags. Wave rows = wave*64..+63; later P-writes hit only our
  // own rows (disjoint across waves), so no extra barrier is needed after this.
  bf8v bq[4][2];  // [qt][ks]
#pragma unroll
  for (int qt = 0; qt < 4; ++qt)
#pragma unroll
    for (int ks = 0; ks < 2; ++ks)
      bq[qt][ks] = *(const bf8v*)&Ps[(wave * 64 + qt * 16 + lo) * FSTR + ks * 32 + hi * 8];

  f4v O[4][4] = {};       // [qt][dt]
  f4v acc_l[4] = {};      // row-sums via MFMA x ones (same C/D layout as O)
  union { bf8v v; unsigned short u[8]; } onesu;
#pragma unroll
  for (int i = 0; i < 8; ++i) onesu.u[i] = 0x3F80;  // bf16 1.0
  const bf8v ones = onesu.v;

  for (int kt = 0; kt < 32; ++kt) {
    asm volatile("" ::: "memory");
    __builtin_amdgcn_s_barrier();          // readers of Kt/Vt(kt-1) done
    asm volatile("" ::: "memory");
    kv_write();                            // waits (counted) only on our 4 loads
    if (kt < 31) kv_load(kt + 1);          // next tile stays in flight across barriers
    asm volatile("s_waitcnt lgkmcnt(0)" ::: "memory");
    __builtin_amdgcn_s_barrier();          // Kt/Vt(kt) visible
    asm volatile("" ::: "memory");

    // ---- S^T = K . Q~^T, ct-outer: one 16-key strip at a time (4 live s-frags)
#pragma unroll
    for (int ct = 0; ct < 4; ++ct) {
      f4v s[4] = {{}, {}, {}, {}};
      __builtin_amdgcn_s_setprio(1);
#pragma unroll
      for (int ks = 0; ks < 2; ++ks) {
        bf8v ak = *(const bf8v*)&Kt[(ct * 16 + lo) * FSTR + ks * 32 + hi * 8];
#pragma unroll
        for (int qt = 0; qt < 4; ++qt)
          s[qt] = __builtin_amdgcn_mfma_f32_16x16x32_bf16(ak, bq[qt][ks], s[qt], 0, 0, 0);
      }
      __builtin_amdgcn_s_setprio(0);
#pragma unroll
      for (int qt = 0; qt < 4; ++qt) {
        float p0 = exp2_hw(s[qt][0]), p1 = exp2_hw(s[qt][1]);
        float p2 = exp2_hw(s[qt][2]), p3 = exp2_hw(s[qt][3]);
        uint2 w; w.x = pk2bf(p0, p1); w.y = pk2bf(p2, p3);
        *(uint2*)&Ps[(wave * 64 + qt * 16 + lo) * FSTR + ct * 16 + hi * 4] = w;
      }
    }

    // ---- O += P.V ; l += P.1
#pragma unroll
    for (int ks = 0; ks < 2; ++ks) {
      bf8v ap[4];
#pragma unroll
      for (int qt = 0; qt < 4; ++qt)
        ap[qt] = *(const bf8v*)&Ps[(wave * 64 + qt * 16 + lo) * FSTR + ks * 32 + hi * 8];
      __builtin_amdgcn_s_setprio(1);
#pragma unroll
      for (int qt = 0; qt < 4; ++qt)
        acc_l[qt] = __builtin_amdgcn_mfma_f32_16x16x32_bf16(ap[qt], ones, acc_l[qt], 0, 0, 0);
#pragma unroll
      for (int dt = 0; dt < 4; ++dt) {
        bf8v bv = *(const bf8v*)&Vt[(dt * 16 + lo) * FSTR + ks * 32 + hi * 8];
#pragma unroll
        for (int qt = 0; qt < 4; ++qt)
          O[qt][dt] = __builtin_amdgcn_mfma_f32_16x16x32_bf16(ap[qt], bv, O[qt][dt], 0, 0, 0);
      }
      __builtin_amdgcn_s_setprio(0);
    }
  }

  // epilogue: acc_l matches O's C/D layout -> no cross-lane reduction
#pragma unroll
  for (int qt = 0; qt < 4; ++qt) {
#pragma unroll
    for (int r = 0; r < 4; ++r) {
      float inv = 1.f / acc_l[qt][r];
      int row = q0 + wave * 64 + qt * 16 + hi * 4 + r;
      size_t orow = ((size_t)b * 2048 + row) * 1024 + h * 64;
#pragma unroll
      for (int dt = 0; dt < 4; ++dt)
        y[orow + dt * 16 + lo] = f2bf(O[qt][dt][r] * inv);
    }
  }
}

// ---------------- launch ----------------
extern "C" void kernel_launch(void* const* d_in, const int* in_sizes, int n_in,
                              void* d_out, int out_size, void* d_ws, size_t ws_size,
                              hipStream_t stream) {
  (void)in_sizes; (void)n_in; (void)out_size; (void)ws_size;
  const float* x     = (const float*)d_in[0];
  const float* w_in  = (const float*)d_in[1];
  const float* b_in  = (const float*)d_in[2];
  const float* w_out = (const float*)d_in[3];
  const float* b_out = (const float*)d_in[4];

  // workspace layout (bf16 elements): vtg aliases xb (xb dead after gemm1)
  unsigned short* xb  = (unsigned short*)d_ws;          // 8192x1024 (later: vtg 64x64x2048)
  unsigned short* wiT = xb  + (size_t)8192 * 1024;      // 3072x1024 (w_in^T)
  unsigned short* woT = wiT + (size_t)3072 * 1024;      // 1024x1024 (w_out^T)
  unsigned short* qkv = woT + (size_t)1024 * 1024;      // 8192x3072
  unsigned short* yb  = qkv + (size_t)8192 * 3072;      // 8192x1024
  unsigned short* vtg = xb;                             // alias: 64*64*2048 == 8192*1024

  // cast + weight transpose fused (one launch)
  prep_kernel<<<12288, 256, 0, stream>>>(x, w_in, w_out, xb, wiT, woT);

  // qkv = x @ w_in + b_in; Q columns (<1024) scaled by log2(e) for exp2 softmax
  gemm_bt256<<<384, 512, 0, stream>>>(xb, wiT, b_in, qkv, 3072, 1024, 12, 1024, L2E);
  // vtg[b][h][d][n] = V^T  (xb is dead now; reuse its space)
  transpose_v_kernel<<<dim3(64, 2, 64), dim3(32, 8), 0, stream>>>(qkv, vtg);
  // attention -> yb
  flash_attn<<<512, 256, 0, stream>>>(qkv, vtg, yb);
  // out = yb @ w_out + b_out  (M=8192, N=1024, K=1024), fp32 out
  gemm_bt_sm<<<dim3(8, 128), 256, 0, stream>>>(yb, woT, b_out, (float*)d_out,
                                               8192, 1024, 1024);
}

// Round 5
// 278.616 us; speedup vs baseline: 1.0965x; 1.0567x over previous
//
#include <hip/hip_runtime.h>
#include <hip/hip_bf16.h>
#include <stdint.h>

typedef __attribute__((ext_vector_type(8))) __bf16 bf8v;   // MFMA A/B frag: 8 bf16 = 4 VGPR
typedef __attribute__((ext_vector_type(4))) float f4v;     // MFMA C/D frag

#define L2E 1.44269504088896f

// fp32 -> bf16 round-to-nearest-even (bit pattern as ushort)
__device__ __forceinline__ unsigned short f2bf(float f) {
  union { float f; unsigned u; } v; v.f = f;
  unsigned r = v.u + 0x7fffu + ((v.u >> 16) & 1u);
  return (unsigned short)(r >> 16);
}

// pack two fp32 -> dword of two RNE bf16 (low = f0), HW v_cvt_pk_bf16_f32 path
__device__ __forceinline__ unsigned pk2bf(float f0, float f1) {
  union { __hip_bfloat162 h; unsigned u; } c;
  c.h = __float22bfloat162_rn(make_float2(f0, f1));
  return c.u;
}

// 2^x via v_exp_f32
__device__ __forceinline__ float exp2_hw(float x) {
  return __builtin_amdgcn_exp2f(x);
}

// async global->LDS, 16B per lane; LDS dest = wave-uniform base + lane*16
__device__ __forceinline__ void gl_lds16(const void* g, void* l) {
  __builtin_amdgcn_global_load_lds(
      (__attribute__((address_space(1))) void*)(g),
      (__attribute__((address_space(3))) void*)(l), 16, 0, 0);
}

__device__ __forceinline__ void store_out(unsigned short* p, float v) { *p = f2bf(v); }
__device__ __forceinline__ void store_out(float* p, float v) { *p = v; }

// ---------------- fused prep: cast x -> bf16  +  weight transpose/cast ----------------
__global__ void prep_kernel(const float* __restrict__ x,
                            const float* __restrict__ w_in,
                            const float* __restrict__ w_out,
                            unsigned short* __restrict__ xb,
                            unsigned short* __restrict__ wiT,
                            unsigned short* __restrict__ woT) {
  __shared__ float tile[32][33];
  int bx = blockIdx.x;
  if (bx < 8192) {
    int i = bx * 256 + threadIdx.x;
    float4 v = ((const float4*)x)[i];
    ushort4 o;
    o.x = f2bf(v.x); o.y = f2bf(v.y); o.z = f2bf(v.z); o.w = f2bf(v.w);
    ((ushort4*)xb)[i] = o;
    return;
  }
  int idx = bx - 8192;              // 0..4095 -> (128 x, 32 y)
  int bxx = idx & 127, byy = idx >> 7;
  const float* in; unsigned short* out; int C, c0;
  if (bxx < 96) { in = w_in;  out = wiT; C = 3072; c0 = bxx * 32; }
  else          { in = w_out; out = woT; C = 1024; c0 = (bxx - 96) * 32; }
  int r0 = byy * 32;
  int tx = threadIdx.x & 31, ty = threadIdx.x >> 5;
#pragma unroll
  for (int j = 0; j < 4; ++j)
    tile[ty + 8 * j][tx] = in[(size_t)(r0 + ty + 8 * j) * C + c0 + tx];
  __syncthreads();
#pragma unroll
  for (int j = 0; j < 4; ++j)
    out[(size_t)(c0 + ty + 8 * j) * 1024 + r0 + tx] = f2bf(tile[tx][ty + 8 * j]);
}

// ---------------- V transpose: qkv v-part -> vtg[b][h][d][n] (bf16) ----------------
__global__ void transpose_v_kernel(const unsigned short* __restrict__ qkv,
                                   unsigned short* __restrict__ vtg) {
  __shared__ unsigned short tile[32][33];
  int bh = blockIdx.z;            // b*16 + h
  int d0 = blockIdx.y * 32;       // 0 or 32
  int n0 = blockIdx.x * 32;
  int b = bh >> 4, h = bh & 15;
  int tx = threadIdx.x, ty = threadIdx.y;
  const unsigned short* src = qkv + (size_t)b * 2048 * 3072 + 2048 + h * 64 + d0;
#pragma unroll
  for (int j = 0; j < 4; ++j)
    tile[ty + 8 * j][tx] = src[(size_t)(n0 + ty + 8 * j) * 3072 + tx];
  __syncthreads();
  unsigned short* dst = vtg + ((size_t)bh * 64) * 2048;
#pragma unroll
  for (int j = 0; j < 4; ++j)
    dst[(size_t)(d0 + ty + 8 * j) * 2048 + n0 + tx] = tile[tx][ty + 8 * j];
}

// ---------------- GEMM: 256x128 tile, BK=64, deep pipeline, templated output ----------------
// C = A(MxK)*BT(NxK)^T + bias. 8 waves (4M x 2N), per-wave 64x64 = acc[4][4].
// LDS 96 KiB: A[2][256x64] + B[2][128x64] (1 block/CU). Grid must be %8==0 and
// sized to a whole number of dispatch rounds (768 for gemm1, 256 for gemm2).
// Full 3-bit XOR swizzle: LDS[row][c] = G[row][c ^ (row&7)] (chunks of 8 shorts),
// applied on the global source of gl_lds (linear LDS dest) and on ds_read cols.
template <typename OutT, bool SCALE>
__global__ __launch_bounds__(512, 2) void gemm256(
    const unsigned short* __restrict__ A,
    const unsigned short* __restrict__ BT,
    const float* __restrict__ bias,
    OutT* __restrict__ C,
    int N, int K, int nbx, int scale_ncols, float scale) {
  __shared__ __align__(16) unsigned short As[2][256 * 64];
  __shared__ __align__(16) unsigned short Bs[2][128 * 64];
  const int tid = threadIdx.x;
  const int wave = tid >> 6, lane = tid & 63;
  const int lo = lane & 15, hi = lane >> 4;
  const int wm = wave >> 1, wn = wave & 1;

  // XCD-aware swizzle (grid %8 == 0)
  const int cpx = gridDim.x >> 3;
  const int s = (blockIdx.x & 7) * cpx + (blockIdx.x >> 3);
  const int by = s / nbx, bx = s - by * nbx;
  const int m0 = by * 256, n0 = bx * 128;

  // staging: per gl_lds call, 512 threads cover 64 rows x 64 k.
  // lane -> row srow=lane>>3, chunk c=lane&7; source chunk pre-swizzled c^(row&7).
  const int srow = lane >> 3;
  const int scol = (((lane & 7) ^ (srow & 7)) * 8);
  const unsigned short* gA = A + (size_t)(m0 + wave * 8 + srow) * K + scol;
  const unsigned short* gB = BT + (size_t)(n0 + wave * 8 + srow) * K + scol;

  // ds_read col (shorts) for ks-half: chunk (ks*4+hi) ^ (row&7), row&7 = lo&7
  const int csw0 = ((hi ^ (lo & 7)) * 8);
  const int csw1 = (((4 + hi) ^ (lo & 7)) * 8);
  const int rA = wm * 64;   // + i*16 + lo
  const int rB = wn * 64;   // + j*16 + lo

  f4v acc[4][4] = {};
  const int nt = K >> 6;

  // prologue: stage tile 0 into parity 0 (A: 4 calls, B: 2 calls)
#pragma unroll
  for (int j = 0; j < 4; ++j)
    gl_lds16(gA + (size_t)(j * 64) * K, &As[0][(j * 64 + wave * 8) * 64]);
#pragma unroll
  for (int j = 0; j < 2; ++j)
    gl_lds16(gB + (size_t)(j * 64) * K, &Bs[0][(j * 64 + wave * 8) * 64]);

  for (int t = 0; t < nt; ++t) {
    const int c = t & 1;
    __builtin_amdgcn_s_barrier();   // readers of parity c^1 (tile t-1) done
    __builtin_amdgcn_sched_barrier(0);
    if (t + 1 < nt) {
      const unsigned short* gA1 = gA + (size_t)(t + 1) * 64;
      const unsigned short* gB1 = gB + (size_t)(t + 1) * 64;
#pragma unroll
      for (int j = 0; j < 4; ++j)
        gl_lds16(gA1 + (size_t)(j * 64) * K, &As[c ^ 1][(j * 64 + wave * 8) * 64]);
#pragma unroll
      for (int j = 0; j < 2; ++j)
        gl_lds16(gB1 + (size_t)(j * 64) * K, &Bs[c ^ 1][(j * 64 + wave * 8) * 64]);
      asm volatile("s_waitcnt vmcnt(6)" ::: "memory");  // tile t landed; t+1 in flight
    } else {
      asm volatile("s_waitcnt vmcnt(0)" ::: "memory");
    }
    __builtin_amdgcn_sched_barrier(0);
    __builtin_amdgcn_s_barrier();   // all waves' tile-t data visible
    __builtin_amdgcn_sched_barrier(0);

    // B fragments for the whole tile (8 x ds_read_b128)
    bf8v b[4][2];
#pragma unroll
    for (int fn = 0; fn < 4; ++fn) {
      b[fn][0] = *(const bf8v*)&Bs[c][(rB + fn * 16 + lo) * 64 + csw0];
      b[fn][1] = *(const bf8v*)&Bs[c][(rB + fn * 16 + lo) * 64 + csw1];
    }
    // 2 phases: A-pair (4 x ds_read_b128) + 16 MFMA each
#pragma unroll
    for (int p = 0; p < 2; ++p) {
      bf8v a[2][2];
#pragma unroll
      for (int i = 0; i < 2; ++i) {
        a[i][0] = *(const bf8v*)&As[c][(rA + (p * 2 + i) * 16 + lo) * 64 + csw0];
        a[i][1] = *(const bf8v*)&As[c][(rA + (p * 2 + i) * 16 + lo) * 64 + csw1];
      }
      __builtin_amdgcn_s_setprio(1);
#pragma unroll
      for (int ks = 0; ks < 2; ++ks)
#pragma unroll
        for (int i = 0; i < 2; ++i)
#pragma unroll
          for (int fn = 0; fn < 4; ++fn)
            acc[p * 2 + i][fn] = __builtin_amdgcn_mfma_f32_16x16x32_bf16(
                a[i][ks], b[fn][ks], acc[p * 2 + i][fn], 0, 0, 0);
      __builtin_amdgcn_s_setprio(0);
    }
  }

  // epilogue
#pragma unroll
  for (int i = 0; i < 4; ++i) {
#pragma unroll
    for (int r = 0; r < 4; ++r) {
      int row = m0 + wm * 64 + i * 16 + hi * 4 + r;
#pragma unroll
      for (int j = 0; j < 4; ++j) {
        int col = n0 + wn * 64 + j * 16 + lo;
        float v = acc[i][j][r] + bias[col];
        if (SCALE && col < scale_ncols) v *= scale;
        store_out(&C[(size_t)row * N + col], v);
      }
    }
  }
}

// ---------------- flash attention v7 ----------------
// v6 + double-buffered Kt/Vt with ONE barrier per kt (T3 minimal pattern):
//   iter t: kv_write(t+1)->buf[c^1] (regs loaded last iter); kv_load(t+2);
//           compute(t) from buf[c]; lgkmcnt(0); s_barrier.
// Race ledger: buf[c^1] overwrite at kt is safe (its readers finished before
// barrier(kt-1)); buf[c] reads at kt see writes from kt-1 (lgkm(0)+barrier).
// All barriers wave-uniform. LDS 73.7 KiB -> 2 blocks/CU.
#define FSTR 72   // LDS row stride (shorts): 64 payload + 8 pad

__global__ __launch_bounds__(256, 2) void flash_attn(
    const unsigned short* __restrict__ qkv,
    const unsigned short* __restrict__ vtg,
    unsigned short* __restrict__ y) {
  __shared__ __align__(16) unsigned short Ps[256 * FSTR];   // Q stage, then P tile [q][key]
  __shared__ __align__(16) unsigned short Kt[2][64 * FSTR]; // K tiles [key][d], dbuf
  __shared__ __align__(16) unsigned short Vt[2][64 * FSTR]; // V^T tiles [d][key], dbuf
  const int tid = threadIdx.x;
  const int wave = tid >> 6, lane = tid & 63;
  const int lo = lane & 15, hi = lane >> 4;

  // XCD swizzle: 512 blocks; XCD c gets one b, 8 heads (~4MB KV -> L2-resident)
  const int lin = blockIdx.x;
  const int swz = (lin & 7) * 64 + (lin >> 3);
  const int q0 = (swz & 7) << 8;        // 8 q-blocks of 256
  const int h  = (swz >> 3) & 15;
  const int b  = swz >> 7;

  const size_t base = (size_t)b * 2048 * 3072;
  const int qoff = h * 64, koff = 1024 + h * 64;
  const unsigned short* vsrc = vtg + (size_t)(b * 16 + h) * 64 * 2048;

  // ---- K/V staging: reg-held prefetch
  const int m_st = tid >> 3, c_st = tid & 7;
  const unsigned short* kg = qkv + base + koff;
  float4 rk0, rk1, rv0, rv1;
  auto kv_load = [&](int kt) {
    const int mb = kt * 64;
    rk0 = *(const float4*)(kg + (size_t)(mb + m_st) * 3072 + c_st * 8);
    rk1 = *(const float4*)(kg + (size_t)(mb + m_st + 32) * 3072 + c_st * 8);
    rv0 = *(const float4*)(vsrc + (size_t)m_st * 2048 + mb + c_st * 8);
    rv1 = *(const float4*)(vsrc + (size_t)(m_st + 32) * 2048 + mb + c_st * 8);
  };
  auto kv_write = [&](int buf) {
    *(float4*)&Kt[buf][m_st * FSTR + c_st * 8] = rk0;
    *(float4*)&Kt[buf][(m_st + 32) * FSTR + c_st * 8] = rk1;
    *(float4*)&Vt[buf][m_st * FSTR + c_st * 8] = rv0;
    *(float4*)&Vt[buf][(m_st + 32) * FSTR + c_st * 8] = rv1;
  };

  kv_load(0);

  // ---- stage Q~ into Ps region [256][FSTR]
#pragma unroll
  for (int i = 0; i < 8; ++i) {
    int cid = i * 256 + tid;
    int m = cid >> 3, c = cid & 7;
    *(float4*)&Ps[m * FSTR + c * 8] =
        *(const float4*)(qkv + base + (size_t)(q0 + m) * 3072 + qoff + c * 8);
  }
  __syncthreads();
  // preload Q^T B-operand frags (wave-local rows; later P-writes are in-wave ordered)
  bf8v bq[4][2];  // [qt][ks]
#pragma unroll
  for (int qt = 0; qt < 4; ++qt)
#pragma unroll
    for (int ks = 0; ks < 2; ++ks)
      bq[qt][ks] = *(const bf8v*)&Ps[(wave * 64 + qt * 16 + lo) * FSTR + ks * 32 + hi * 8];

  f4v O[4][4] = {};       // [qt][dt]
  f4v acc_l[4] = {};      // row-sums via MFMA x ones (same C/D layout as O)
  union { bf8v v; unsigned short u[8]; } onesu;
#pragma unroll
  for (int i = 0; i < 8; ++i) onesu.u[i] = 0x3F80;  // bf16 1.0
  const bf8v ones = onesu.v;

  // prologue: buf0 <- tile 0; issue tile-1 loads; certify buf0
  kv_write(0);
  kv_load(1);
  asm volatile("s_waitcnt lgkmcnt(0)" ::: "memory");
  __builtin_amdgcn_s_barrier();
  asm volatile("" ::: "memory");

  for (int kt = 0; kt < 32; ++kt) {
    const int c = kt & 1;
    // stage next tile into the other buffer (readers of it finished at barrier(kt-1))
    if (kt < 31) {
      kv_write(c ^ 1);              // regs from kv_load(kt+1); vmcnt dep handled by compiler
      if (kt < 30) kv_load(kt + 2); // issue; stays in flight across barriers
    }

    // ---- S^T = K . Q~^T, ct-outer: one 16-key strip at a time
#pragma unroll
    for (int ct = 0; ct < 4; ++ct) {
      f4v s[4] = {{}, {}, {}, {}};
      __builtin_amdgcn_s_setprio(1);
#pragma unroll
      for (int ks = 0; ks < 2; ++ks) {
        bf8v ak = *(const bf8v*)&Kt[c][(ct * 16 + lo) * FSTR + ks * 32 + hi * 8];
#pragma unroll
        for (int qt = 0; qt < 4; ++qt)
          s[qt] = __builtin_amdgcn_mfma_f32_16x16x32_bf16(ak, bq[qt][ks], s[qt], 0, 0, 0);
      }
      __builtin_amdgcn_s_setprio(0);
#pragma unroll
      for (int qt = 0; qt < 4; ++qt) {
        float p0 = exp2_hw(s[qt][0]), p1 = exp2_hw(s[qt][1]);
        float p2 = exp2_hw(s[qt][2]), p3 = exp2_hw(s[qt][3]);
        uint2 w; w.x = pk2bf(p0, p1); w.y = pk2bf(p2, p3);
        *(uint2*)&Ps[(wave * 64 + qt * 16 + lo) * FSTR + ct * 16 + hi * 4] = w;
      }
    }

    // ---- O += P.V ; l += P.1
#pragma unroll
    for (int ks = 0; ks < 2; ++ks) {
      bf8v ap[4];
#pragma unroll
      for (int qt = 0; qt < 4; ++qt)
        ap[qt] = *(const bf8v*)&Ps[(wave * 64 + qt * 16 + lo) * FSTR + ks * 32 + hi * 8];
      __builtin_amdgcn_s_setprio(1);
#pragma unroll
      for (int qt = 0; qt < 4; ++qt)
        acc_l[qt] = __builtin_amdgcn_mfma_f32_16x16x32_bf16(ap[qt], ones, acc_l[qt], 0, 0, 0);
#pragma unroll
      for (int dt = 0; dt < 4; ++dt) {
        bf8v bv = *(const bf8v*)&Vt[c][(dt * 16 + lo) * FSTR + ks * 32 + hi * 8];
#pragma unroll
        for (int qt = 0; qt < 4; ++qt)
          O[qt][dt] = __builtin_amdgcn_mfma_f32_16x16x32_bf16(ap[qt], bv, O[qt][dt], 0, 0, 0);
      }
      __builtin_amdgcn_s_setprio(0);
    }

    asm volatile("s_waitcnt lgkmcnt(0)" ::: "memory");
    __builtin_amdgcn_s_barrier();   // single barrier per kt
    asm volatile("" ::: "memory");
  }

  // epilogue: acc_l matches O's C/D layout -> no cross-lane reduction
#pragma unroll
  for (int qt = 0; qt < 4; ++qt) {
#pragma unroll
    for (int r = 0; r < 4; ++r) {
      float inv = 1.f / acc_l[qt][r];
      int row = q0 + wave * 64 + qt * 16 + hi * 4 + r;
      size_t orow = ((size_t)b * 2048 + row) * 1024 + h * 64;
#pragma unroll
      for (int dt = 0; dt < 4; ++dt)
        y[orow + dt * 16 + lo] = f2bf(O[qt][dt][r] * inv);
    }
  }
}

// ---------------- launch ----------------
extern "C" void kernel_launch(void* const* d_in, const int* in_sizes, int n_in,
                              void* d_out, int out_size, void* d_ws, size_t ws_size,
                              hipStream_t stream) {
  (void)in_sizes; (void)n_in; (void)out_size; (void)ws_size;
  const float* x     = (const float*)d_in[0];
  const float* w_in  = (const float*)d_in[1];
  const float* b_in  = (const float*)d_in[2];
  const float* w_out = (const float*)d_in[3];
  const float* b_out = (const float*)d_in[4];

  // workspace layout (bf16 elements): vtg aliases xb (xb dead after gemm1)
  unsigned short* xb  = (unsigned short*)d_ws;          // 8192x1024 (later: vtg 64x64x2048)
  unsigned short* wiT = xb  + (size_t)8192 * 1024;      // 3072x1024 (w_in^T)
  unsigned short* woT = wiT + (size_t)3072 * 1024;      // 1024x1024 (w_out^T)
  unsigned short* qkv = woT + (size_t)1024 * 1024;      // 8192x3072
  unsigned short* yb  = qkv + (size_t)8192 * 3072;      // 8192x1024
  unsigned short* vtg = xb;                             // alias: 64*64*2048 == 8192*1024

  // cast + weight transpose fused (one launch)
  prep_kernel<<<12288, 256, 0, stream>>>(x, w_in, w_out, xb, wiT, woT);

  // qkv = x @ w_in + b_in; Q columns (<1024) scaled by log2(e) for exp2 softmax
  // 256x128 tiles: grid 32x24 = 768 blocks = exactly 3 rounds at 1 block/CU
  gemm256<unsigned short, true><<<768, 512, 0, stream>>>(
      xb, wiT, b_in, qkv, 3072, 1024, 24, 1024, L2E);
  // vtg[b][h][d][n] = V^T  (xb is dead now; reuse its space)
  transpose_v_kernel<<<dim3(64, 2, 64), dim3(32, 8), 0, stream>>>(qkv, vtg);
  // attention -> yb
  flash_attn<<<512, 256, 0, stream>>>(qkv, vtg, yb);
  // out = yb @ w_out + b_out; 256x128 tiles: grid 32x8 = 256 blocks = 1 round
  gemm256<float, false><<<256, 512, 0, stream>>>(
      yb, woT, b_out, (float*)d_out, 1024, 1024, 8, 0, 1.0f);
}